// Round 13
// baseline (302.775 us; speedup 1.0000x reference)
//
#include <hip/hip_runtime.h>

#define N_NODES   100000
#define N_EDGES   1600000
#define NFEAT     128
#define NGRAPHS   2048
#define CBSHIFT   8                        // 256 nodes per coarse bucket
#define NCB       ((N_NODES + 255) / 256)  // 391
#define P1_EPB    8192                     // edges per p1 block
#define P1_BLOCKS ((N_EDGES + P1_EPB - 1) / P1_EPB)   // 196
#define GEMM_BLOCKS 782
#define BH_BLOCKS   64
#define DP_BLOCKS 100
#define DP_NPB    ((N_NODES + DP_BLOCKS - 1) / DP_BLOCKS)   // 1000
#define G1_BLOCKS 2048
#define ZCNT      (NGRAPHS + NCB + 64 + 512 + NCB)   // gsum|alloc|dalloc|dcount(8x64)|bcount

typedef __attribute__((ext_vector_type(8))) short short8;
typedef __attribute__((ext_vector_type(4))) float f32x4;

// RNE float -> bf16 (finite inputs)
__device__ __forceinline__ unsigned short f2bf(float f) {
    unsigned int u = __float_as_uint(f);
    u += 0x7FFFu + ((u >> 16) & 1u);
    return (unsigned short)(u >> 16);
}

// acc[k] += s * bf16[k]  (8 bf16 packed in uint4)
__device__ __forceinline__ void acc8s(float* acc, uint4 v, float s) {
    acc[0] = fmaf(s, __uint_as_float(v.x << 16), acc[0]);
    acc[1] = fmaf(s, __uint_as_float(v.x & 0xFFFF0000u), acc[1]);
    acc[2] = fmaf(s, __uint_as_float(v.y << 16), acc[2]);
    acc[3] = fmaf(s, __uint_as_float(v.y & 0xFFFF0000u), acc[3]);
    acc[4] = fmaf(s, __uint_as_float(v.z << 16), acc[4]);
    acc[5] = fmaf(s, __uint_as_float(v.z & 0xFFFF0000u), acc[5]);
    acc[6] = fmaf(s, __uint_as_float(v.w << 16), acc[6]);
    acc[7] = fmaf(s, __uint_as_float(v.w & 0xFFFF0000u), acc[7]);
}

// ---------------- setup: 0-15 WT1 prep, 16 w2l/c2, 17.. bucket histogram ----------------
__global__ __launch_bounds__(256) void k_setup(const float* __restrict__ W1,
                                               unsigned short* __restrict__ WT1,
                                               const float* __restrict__ W2,
                                               const float* __restrict__ Wlin,
                                               const float* __restrict__ b2,
                                               const float* __restrict__ blin,
                                               float* __restrict__ w2l,
                                               const int* __restrict__ dst,
                                               int* __restrict__ bcount) {
    const int blk = blockIdx.x;
    const int t = threadIdx.x;
    if (blk < 16) {
        int base = blk * 1024 + t * 4;
        #pragma unroll
        for (int q = 0; q < 4; ++q) {
            int i = base + q;
            int n = i >> 7, k = i & 127;
            WT1[i] = f2bf(W1[k * 128 + n]);
        }
    } else if (blk == 16) {
        __shared__ float s[256];
        // w2l[i] = W2[i,:] . Wlin, 2 threads per output
        int i = t >> 1, half = t & 1;
        float ps = 0.f;
        for (int j = half * 64; j < half * 64 + 64; ++j)
            ps += W2[i * 128 + j] * Wlin[j];
        s[t] = ps;
        __syncthreads();
        if (!half) w2l[i] = s[t] + s[t + 1];
        __syncthreads();
        // c2 = b2 . Wlin + blin
        float pc = (t < 128) ? b2[t] * Wlin[t] : 0.f;
        s[t] = pc;
        __syncthreads();
        for (int off = 128; off > 0; off >>= 1) {
            if (t < off) s[t] += s[t + off];
            __syncthreads();
        }
        if (t == 0) w2l[128] = s[0] + blin[0];
    } else {
        // bucket histogram, BH_BLOCKS blocks
        __shared__ int h[NCB];
        for (int i = t; i < NCB; i += 256) h[i] = 0;
        __syncthreads();
        int b = blk - 17;
        int stride = BH_BLOCKS * 256;
        for (int e = b * 256 + t; e < N_EDGES; e += stride)
            atomicAdd(&h[dst[e] >> CBSHIFT], 1);
        __syncthreads();
        for (int i = t; i < NCB; i += 256) {
            int v = h[i];
            if (v) atomicAdd(&bcount[i], v);
        }
    }
}

// ---------------- fused: LDS-free MFMA GEMM (unscaled)  ||  p1 scatter ----------------
__global__ __launch_bounds__(256) void k_gemm_p1(const float* __restrict__ X,
                                                 const unsigned short* __restrict__ WT,
                                                 unsigned short* __restrict__ C,
                                                 const int* __restrict__ src,
                                                 const int* __restrict__ dst,
                                                 const int* __restrict__ bcount,
                                                 int* __restrict__ bstart,
                                                 int* __restrict__ alloc,
                                                 unsigned int* __restrict__ pairs) {
    if (blockIdx.x >= GEMM_BLOCKS) {
        // ---- p1: self-scanning block-ranked scatter ----
        __shared__ int hist[NCB], base[NCB], cur[NCB], bst[NCB], s[256];
        const int pb = blockIdx.x - GEMM_BLOCKS;
        const int t = threadIdx.x;
        for (int i = t; i < NCB; i += 256) { hist[i] = 0; cur[i] = 0; }
        int v0 = (2 * t < NCB) ? bcount[2 * t] : 0;
        int v1 = (2 * t + 1 < NCB) ? bcount[2 * t + 1] : 0;
        int local = v0 + v1;
        s[t] = local;
        __syncthreads();
        for (int off = 1; off < 256; off <<= 1) {
            int x = (t >= off) ? s[t - off] : 0;
            __syncthreads();
            s[t] += x;
            __syncthreads();
        }
        int excl = s[t] - local;
        if (2 * t < NCB)     bst[2 * t] = excl;
        if (2 * t + 1 < NCB) bst[2 * t + 1] = excl + v0;
        if (pb == 0) {
            if (2 * t < NCB)     bstart[2 * t] = excl;
            if (2 * t + 1 < NCB) bstart[2 * t + 1] = excl + v0;
            if (t == 255) bstart[NCB] = s[255];
        }
        __syncthreads();
        const int e0 = pb * P1_EPB;
        const int e1 = min(e0 + P1_EPB, N_EDGES);
        for (int e = e0 + t; e < e1; e += 256)
            atomicAdd(&hist[dst[e] >> CBSHIFT], 1);
        __syncthreads();
        // staggered reservation order: spread per-bin atomic queues
        const int off0 = (pb * 89) % NCB;
        for (int k = t; k < NCB; k += 256) {
            int i = k + off0;
            if (i >= NCB) i -= NCB;
            int c = hist[i];
            base[i] = c ? (bst[i] + atomicAdd(&alloc[i], c)) : 0;
        }
        __syncthreads();
        for (int e = e0 + t; e < e1; e += 256) {
            int d = dst[e];
            int b = d >> CBSHIFT;
            int r = atomicAdd(&cur[b], 1);
            pairs[base[b] + r] = (unsigned int)src[e] | ((unsigned int)(d & 255) << 17);
        }
        return;
    }
    // ---- GEMM: C[r,:] = bf16(X[r,:] @ W1), no LDS, B frags via L2 ----
    const int tid  = threadIdx.x;
    const int R0   = blockIdx.x * 128;
    const int wv   = tid >> 6;
    const int lane = tid & 63;
    const int m16  = lane & 15;
    const int quad = lane >> 4;
    const int r0 = R0 + wv * 32 + m16;
    const int r1 = r0 + 16;
    const bool ok0 = r0 < N_NODES, ok1 = r1 < N_NODES;

    f32x4 acc[2][8] = {};
    #pragma unroll
    for (int ks = 0; ks < 4; ++ks) {
        const int k0 = ks * 32 + quad * 8;
        short8 a0 = {}, a1 = {};
        if (ok0) {
            float4 f0 = *(const float4*)(X + (size_t)r0 * NFEAT + k0);
            float4 f1 = *(const float4*)(X + (size_t)r0 * NFEAT + k0 + 4);
            a0[0] = (short)f2bf(f0.x); a0[1] = (short)f2bf(f0.y);
            a0[2] = (short)f2bf(f0.z); a0[3] = (short)f2bf(f0.w);
            a0[4] = (short)f2bf(f1.x); a0[5] = (short)f2bf(f1.y);
            a0[6] = (short)f2bf(f1.z); a0[7] = (short)f2bf(f1.w);
        }
        if (ok1) {
            float4 f0 = *(const float4*)(X + (size_t)r1 * NFEAT + k0);
            float4 f1 = *(const float4*)(X + (size_t)r1 * NFEAT + k0 + 4);
            a1[0] = (short)f2bf(f0.x); a1[1] = (short)f2bf(f0.y);
            a1[2] = (short)f2bf(f0.z); a1[3] = (short)f2bf(f0.w);
            a1[4] = (short)f2bf(f1.x); a1[5] = (short)f2bf(f1.y);
            a1[6] = (short)f2bf(f1.z); a1[7] = (short)f2bf(f1.w);
        }
        #pragma unroll
        for (int ct = 0; ct < 8; ++ct) {
            short8 bb = *(const short8*)(WT + (ct * 16 + m16) * 128 + k0);
            acc[0][ct] = __builtin_amdgcn_mfma_f32_16x16x32_bf16(a0, bb, acc[0][ct], 0, 0, 0);
            acc[1][ct] = __builtin_amdgcn_mfma_f32_16x16x32_bf16(a1, bb, acc[1][ct], 0, 0, 0);
        }
    }
    #pragma unroll
    for (int t2 = 0; t2 < 2; ++t2) {
        int rbase = R0 + wv * 32 + t2 * 16 + quad * 4;
        #pragma unroll
        for (int reg = 0; reg < 4; ++reg) {
            int gr = rbase + reg;
            if (gr < N_NODES) {
                #pragma unroll
                for (int ct = 0; ct < 8; ++ct)
                    C[(size_t)gr * NFEAT + ct * 16 + m16] = f2bf(acc[t2][ct][reg]);
            }
        }
    }
}

// ---------------- pass 2: per-bucket sort -> csr_src, row_start, indeg, dinv (+sharded deg hist) ----------------
__global__ __launch_bounds__(256) void k_p2(const unsigned int* __restrict__ pairs,
                                            const int* __restrict__ bstart,
                                            int* __restrict__ csr_src,
                                            int* __restrict__ row_start,
                                            int* __restrict__ indeg,
                                            float* __restrict__ dinv,
                                            int* __restrict__ dcount) {
    __shared__ int hist[256], sst[256], cur[256], s[256], dh[64];
    const int b = blockIdx.x;
    const int t = threadIdx.x;
    const int beg = bstart[b];
    const int end = bstart[b + 1];
    hist[t] = 0; cur[t] = 0;
    if (t < 64) dh[t] = 0;
    __syncthreads();
    for (int i = beg + t; i < end; i += 256)
        atomicAdd(&hist[pairs[i] >> 17], 1);
    __syncthreads();
    int v = hist[t];
    s[t] = v;
    __syncthreads();
    for (int off = 1; off < 256; off <<= 1) {
        int x = (t >= off) ? s[t - off] : 0;
        __syncthreads();
        s[t] += x;
        __syncthreads();
    }
    sst[t] = s[t] - v;
    __syncthreads();
    {
        int node = (b << CBSHIFT) + t;
        if (node < N_NODES) {
            row_start[node] = beg + sst[t];
            indeg[node] = v;
            dinv[node] = rsqrtf((float)v + 1.0f);
            atomicAdd(&dh[63 - min(v, 63)], 1);
        }
    }
    for (int i = beg + t; i < end; i += 256) {
        unsigned int pv = pairs[i];
        int dl = pv >> 17;
        int r = atomicAdd(&cur[dl], 1);
        csr_src[beg + sst[dl] + r] = (int)(pv & 0x1FFFFu);
    }
    __syncthreads();
    if (t < 64 && dh[t]) atomicAdd(&dcount[((b & 7) << 6) + t], dh[t]);   // 8-sharded
}

// ---------------- degree permutation (descending), self-scanning over 8 shards ----------------
__global__ __launch_bounds__(256) void k_dperm(const int* __restrict__ indeg,
                                               const int* __restrict__ dcount,
                                               int* __restrict__ dalloc,
                                               int* __restrict__ perm) {
    __shared__ int h[64], base[64], cur[64], s[64];
    const int t = threadIdx.x;
    int v = 0;
    if (t < 64) {
        h[t] = 0; cur[t] = 0;
        #pragma unroll
        for (int sh = 0; sh < 8; ++sh) v += dcount[(sh << 6) + t];
        s[t] = v;
    }
    __syncthreads();
    for (int off = 1; off < 64; off <<= 1) {
        int x = (t >= off && t < 64) ? s[t - off] : 0;
        __syncthreads();
        if (t < 64) s[t] += x;
        __syncthreads();
    }
    int myst = (t < 64) ? s[t] - v : 0;
    const int i0 = blockIdx.x * DP_NPB;
    const int i1 = min(i0 + DP_NPB, N_NODES);
    for (int i = i0 + t; i < i1; i += 256)
        atomicAdd(&h[63 - min(indeg[i], 63)], 1);
    __syncthreads();
    if (t < 64) {
        int c = h[t];
        base[t] = c ? (myst + atomicAdd(&dalloc[t], c)) : 0;
    }
    __syncthreads();
    for (int i = i0 + t; i < i1; i += 256) {
        int bin = 63 - min(indeg[i], 63);
        int r = atomicAdd(&cur[bin], 1);
        perm[base[bin] + r] = i;
    }
}

// ---------------- gather layer 1 (per-edge dinv) + fused z projection; persistent ----------------
__global__ __launch_bounds__(256) void k_gather1(const unsigned short* __restrict__ xwb,
                                                 const int* __restrict__ csr_src,
                                                 const int* __restrict__ row_start,
                                                 const int* __restrict__ indeg,
                                                 const float* __restrict__ dinv,
                                                 const float* __restrict__ b,
                                                 const float* __restrict__ w2l,
                                                 const int* __restrict__ perm,
                                                 float* __restrict__ z) {
    const int lane  = threadIdx.x & 63;
    const int p     = lane & 15;
    const int gbase = lane & 48;
    const int ngroups = G1_BLOCKS * 16;
    int gid = blockIdx.x * 16 + (threadIdx.x >> 4);
    const uint4* tab = (const uint4*)xwb;
    float4 b0 = *(const float4*)(b + p * 8);
    float4 b1 = *(const float4*)(b + p * 8 + 4);
    float4 w0 = *(const float4*)(w2l + p * 8);
    float4 w1 = *(const float4*)(w2l + p * 8 + 4);

    for (int nidx = gid; nidx < N_NODES; nidx += ngroups) {
        int node = perm[nidx];
        const int beg = row_start[node];
        const int cnt = indeg[node];
        float dvn = dinv[node];
        float acc[8] = {};
        acc8s(acc, tab[(size_t)node * 16 + p], dvn);     // self loop
        int j = 0;
        #pragma unroll 1
        for (; j + 8 <= cnt; j += 8) {
            int   my   = csr_src[beg + j + (p & 7)];
            float mydv = dinv[my];
            uint4 v[8];
            #pragma unroll
            for (int q = 0; q < 8; ++q) {
                int idx = __shfl(my, gbase + q);
                v[q] = tab[(size_t)idx * 16 + p];
            }
            #pragma unroll
            for (int q = 0; q < 8; ++q) {
                float sv = __shfl(mydv, gbase + q);
                acc8s(acc, v[q], sv);
            }
        }
        #pragma unroll 1
        for (; j < cnt; ++j) {
            int idx = csr_src[beg + j];
            float sv = dinv[idx];
            acc8s(acc, tab[(size_t)idx * 16 + p], sv);
        }
        float s = fmaxf(acc[0] * dvn + b0.x, 0.f) * w0.x
                + fmaxf(acc[1] * dvn + b0.y, 0.f) * w0.y
                + fmaxf(acc[2] * dvn + b0.z, 0.f) * w0.z
                + fmaxf(acc[3] * dvn + b0.w, 0.f) * w0.w
                + fmaxf(acc[4] * dvn + b1.x, 0.f) * w1.x
                + fmaxf(acc[5] * dvn + b1.y, 0.f) * w1.y
                + fmaxf(acc[6] * dvn + b1.z, 0.f) * w1.z
                + fmaxf(acc[7] * dvn + b1.w, 0.f) * w1.w;
        s += __shfl_xor(s, 1);
        s += __shfl_xor(s, 2);
        s += __shfl_xor(s, 4);
        s += __shfl_xor(s, 8);
        if (p == 0) z[node] = s * dvn;
    }
}

// ---------------- layer 2 + pool over scalars ----------------
__global__ __launch_bounds__(256) void k_gather2s(const float* __restrict__ z,
                                                  const int* __restrict__ csr_src,
                                                  const int* __restrict__ row_start,
                                                  const int* __restrict__ indeg,
                                                  const float* __restrict__ dinv,
                                                  const int* __restrict__ perm,
                                                  const int* __restrict__ batch,
                                                  float* __restrict__ gsum) {
    int nidx = blockIdx.x * blockDim.x + threadIdx.x;
    if (nidx >= N_NODES) return;
    int node = perm[nidx];
    const int beg = row_start[node];
    const int cnt = indeg[node];
    float a = z[node];
    int j = 0;
    #pragma unroll 1
    for (; j + 4 <= cnt; j += 4) {
        int i0 = csr_src[beg + j + 0];
        int i1 = csr_src[beg + j + 1];
        int i2 = csr_src[beg + j + 2];
        int i3 = csr_src[beg + j + 3];
        a += z[i0] + z[i1] + z[i2] + z[i3];
    }
    #pragma unroll 1
    for (; j < cnt; ++j)
        a += z[csr_src[beg + j]];
    atomicAdd(&gsum[batch[node]], a * dinv[node]);
}

// ---------------- final: counts via binary search on sorted batch; +c2 ----------------
__global__ void k_final(const float* __restrict__ gsum, const int* __restrict__ batch,
                        const float* __restrict__ c2, float* __restrict__ out) {
    int g = blockIdx.x * blockDim.x + threadIdx.x;
    if (g >= NGRAPHS) return;
    int lo = 0, hi = N_NODES;
    while (lo < hi) { int m = (lo + hi) >> 1; if (batch[m] < g) lo = m + 1; else hi = m; }
    int lb = lo;
    lo = 0; hi = N_NODES;
    int g1 = g + 1;
    while (lo < hi) { int m = (lo + hi) >> 1; if (batch[m] < g1) lo = m + 1; else hi = m; }
    float cnt = (float)(lo - lb);
    out[g] = gsum[g] / fmaxf(cnt, 1.0f) + c2[0];
}

extern "C" void kernel_launch(void* const* d_in, const int* in_sizes, int n_in,
                              void* d_out, int out_size, void* d_ws, size_t ws_size,
                              hipStream_t stream) {
    const float* x    = (const float*)d_in[0];
    const int*   ei   = (const int*)d_in[1];
    const int*   bat  = (const int*)d_in[2];
    const float* W1   = (const float*)d_in[3];
    const float* b1   = (const float*)d_in[4];
    const float* W2   = (const float*)d_in[5];
    const float* b2   = (const float*)d_in[6];
    const float* Wlin = (const float*)d_in[7];
    const float* blin = (const float*)d_in[8];
    float* out = (float*)d_out;

    const int* src = ei;
    const int* dst = ei + N_EDGES;

    // ---- workspace layout ----
    const size_t NF = (size_t)N_NODES * NFEAT;
    unsigned short* bufA = (unsigned short*)d_ws;          // bf16 xw1 table (unscaled)
    float* z       = (float*)(bufA + NF);                  // [N]
    float* dinv    = z + N_NODES;                          // [N]
    int* row_start = (int*)(dinv + N_NODES);               // [N]
    int* indeg     = row_start + N_NODES;                  // [N]
    int* perm      = indeg + N_NODES;                      // [N]
    int* bstart    = perm + N_NODES;                       // [NCB+1]
    // memset-zeroed region (contiguous): gsum | alloc | dalloc | dcount(8x64) | bcount
    float* gsum    = (float*)(bstart + NCB + 1);           // [G]
    int* alloc     = (int*)(gsum + NGRAPHS);               // [NCB]
    int* dalloc    = alloc + NCB;                          // [64]
    int* dcount    = dalloc + 64;                          // [512]
    int* bcount    = dcount + 512;                         // [NCB]
    unsigned short* WT1 = (unsigned short*)(bcount + NCB); // [16384]
    float* w2l     = (float*)(WT1 + 128 * 128);            // [132] (c2 at [128])
    unsigned int* pairs = (unsigned int*)(w2l + 132);      // [E]
    int* csr_src   = (int*)(pairs + N_EDGES);              // [E]

    const int BS = 256;
    int node_blocks = (N_NODES + BS - 1) / BS;

    // ---- zero accumulators, then setup (weights + bucket histogram) ----
    hipMemsetAsync(gsum, 0, ZCNT * sizeof(int), stream);
    k_setup<<<17 + BH_BLOCKS, BS, 0, stream>>>(W1, WT1, W2, Wlin, b2, blin, w2l, dst, bcount);

    // ---- fused GEMM || p1 scatter ----
    k_gemm_p1<<<GEMM_BLOCKS + P1_BLOCKS, BS, 0, stream>>>(x, WT1, bufA, src, dst,
                                                          bcount, bstart, alloc, pairs);

    // ---- per-bucket sort + degree permutation ----
    k_p2<<<NCB, BS, 0, stream>>>(pairs, bstart, csr_src, row_start, indeg, dinv, dcount);
    k_dperm<<<DP_BLOCKS, BS, 0, stream>>>(indeg, dcount, dalloc, perm);

    // ---- layer 1 gather (+ fused layer-2 projection to scalar z) ----
    k_gather1<<<G1_BLOCKS, BS, 0, stream>>>(bufA, csr_src, row_start, indeg, dinv, b1, w2l,
                                            perm, z);

    // ---- layer 2 + pool over scalar z ----
    k_gather2s<<<node_blocks, BS, 0, stream>>>(z, csr_src, row_start, indeg, dinv, perm,
                                               bat, gsum);

    // ---- final ----
    k_final<<<(NGRAPHS + BS - 1) / BS, BS, 0, stream>>>(gsum, bat, w2l + 128, out);
}

// Round 15
// 283.144 us; speedup vs baseline: 1.0693x; 1.0693x over previous
//
#include <hip/hip_runtime.h>

#define N_NODES   100000
#define N_EDGES   1600000
#define NFEAT     128
#define NGRAPHS   2048
#define CBSHIFT   8                        // 256 nodes per coarse bucket
#define NCB       ((N_NODES + 255) / 256)  // 391
#define P1_EPB    8192                     // edges per k_p1 block
#define GEMM_BLOCKS 782
#define BH_BLOCKS   256
#define DP_BLOCKS 100
#define DP_NPB    ((N_NODES + DP_BLOCKS - 1) / DP_BLOCKS)   // 1000
#define G1_BLOCKS 2048
#define ZCNT      (NGRAPHS + NCB + 64 + 512 + NCB)   // gsum|alloc|dalloc|dcount(8x64)|bcount

typedef __attribute__((ext_vector_type(8))) short short8;
typedef __attribute__((ext_vector_type(4))) float f32x4;

// RNE float -> bf16 (finite inputs)
__device__ __forceinline__ unsigned short f2bf(float f) {
    unsigned int u = __float_as_uint(f);
    u += 0x7FFFu + ((u >> 16) & 1u);
    return (unsigned short)(u >> 16);
}

// acc[k] += s * bf16[k]  (8 bf16 packed in uint4)
__device__ __forceinline__ void acc8s(float* acc, uint4 v, float s) {
    acc[0] = fmaf(s, __uint_as_float(v.x << 16), acc[0]);
    acc[1] = fmaf(s, __uint_as_float(v.x & 0xFFFF0000u), acc[1]);
    acc[2] = fmaf(s, __uint_as_float(v.y << 16), acc[2]);
    acc[3] = fmaf(s, __uint_as_float(v.y & 0xFFFF0000u), acc[3]);
    acc[4] = fmaf(s, __uint_as_float(v.z << 16), acc[4]);
    acc[5] = fmaf(s, __uint_as_float(v.z & 0xFFFF0000u), acc[5]);
    acc[6] = fmaf(s, __uint_as_float(v.w << 16), acc[6]);
    acc[7] = fmaf(s, __uint_as_float(v.w & 0xFFFF0000u), acc[7]);
}

// ---------------- multi-role setup: 0-15 WT1 prep, 16 w2l, 17+ zero accumulators ----------------
__global__ __launch_bounds__(256) void k_misc(const float* __restrict__ W1,
                                              unsigned short* __restrict__ WT1,
                                              const float* __restrict__ W2,
                                              const float* __restrict__ Wlin,
                                              const float* __restrict__ b2,
                                              const float* __restrict__ blin,
                                              float* __restrict__ w2l,
                                              int* __restrict__ zeros) {
    const int blk = blockIdx.x;
    const int t = threadIdx.x;
    if (blk < 16) {
        int base = blk * 1024 + t * 4;
        #pragma unroll
        for (int q = 0; q < 4; ++q) {
            int i = base + q;
            int n = i >> 7, k = i & 127;
            WT1[i] = f2bf(W1[k * 128 + n]);
        }
    } else if (blk == 16) {
        __shared__ float s[256];
        // w2l[i] = W2[i,:] . Wlin, 2 threads per output
        int i = t >> 1, half = t & 1;
        float ps = 0.f;
        for (int j = half * 64; j < half * 64 + 64; ++j)
            ps += W2[i * 128 + j] * Wlin[j];
        s[t] = ps;
        __syncthreads();
        if (!half) w2l[i] = s[t] + s[t + 1];
        __syncthreads();
        // c2 = b2 . Wlin + blin
        float pc = (t < 128) ? b2[t] * Wlin[t] : 0.f;
        s[t] = pc;
        __syncthreads();
        for (int off = 128; off > 0; off >>= 1) {
            if (t < off) s[t] += s[t + off];
            __syncthreads();
        }
        if (t == 0) w2l[128] = s[0] + blin[0];
    } else {
        int i = (blk - 17) * 256 + t;
        if (i < ZCNT) zeros[i] = 0;
    }
}

// ---------------- fused: LDS-free MFMA GEMM (unscaled)  ||  coarse bucket histogram ----------------
__global__ __launch_bounds__(256) void k_gemm_bhist(const float* __restrict__ X,
                                                    const unsigned short* __restrict__ WT,
                                                    unsigned short* __restrict__ C,
                                                    const int* __restrict__ dst,
                                                    int* __restrict__ bcount) {
    if (blockIdx.x >= GEMM_BLOCKS) {
        // ---- histogram part ----
        __shared__ int h[NCB];
        for (int i = threadIdx.x; i < NCB; i += 256) h[i] = 0;
        __syncthreads();
        int b = blockIdx.x - GEMM_BLOCKS;
        int stride = BH_BLOCKS * 256;
        for (int e = b * 256 + threadIdx.x; e < N_EDGES; e += stride)
            atomicAdd(&h[dst[e] >> CBSHIFT], 1);
        __syncthreads();
        for (int i = threadIdx.x; i < NCB; i += 256) {
            int v = h[i];
            if (v) atomicAdd(&bcount[i], v);
        }
        return;
    }
    // ---- GEMM part: C[r,:] = bf16(X[r,:] @ W1), no LDS, B frags via L2 ----
    const int tid  = threadIdx.x;
    const int R0   = blockIdx.x * 128;
    const int wv   = tid >> 6;
    const int lane = tid & 63;
    const int m16  = lane & 15;
    const int quad = lane >> 4;
    const int r0 = R0 + wv * 32 + m16;
    const int r1 = r0 + 16;
    const bool ok0 = r0 < N_NODES, ok1 = r1 < N_NODES;

    f32x4 acc[2][8] = {};
    #pragma unroll
    for (int ks = 0; ks < 4; ++ks) {
        const int k0 = ks * 32 + quad * 8;
        short8 a0 = {}, a1 = {};
        if (ok0) {
            float4 f0 = *(const float4*)(X + (size_t)r0 * NFEAT + k0);
            float4 f1 = *(const float4*)(X + (size_t)r0 * NFEAT + k0 + 4);
            a0[0] = (short)f2bf(f0.x); a0[1] = (short)f2bf(f0.y);
            a0[2] = (short)f2bf(f0.z); a0[3] = (short)f2bf(f0.w);
            a0[4] = (short)f2bf(f1.x); a0[5] = (short)f2bf(f1.y);
            a0[6] = (short)f2bf(f1.z); a0[7] = (short)f2bf(f1.w);
        }
        if (ok1) {
            float4 f0 = *(const float4*)(X + (size_t)r1 * NFEAT + k0);
            float4 f1 = *(const float4*)(X + (size_t)r1 * NFEAT + k0 + 4);
            a1[0] = (short)f2bf(f0.x); a1[1] = (short)f2bf(f0.y);
            a1[2] = (short)f2bf(f0.z); a1[3] = (short)f2bf(f0.w);
            a1[4] = (short)f2bf(f1.x); a1[5] = (short)f2bf(f1.y);
            a1[6] = (short)f2bf(f1.z); a1[7] = (short)f2bf(f1.w);
        }
        #pragma unroll
        for (int ct = 0; ct < 8; ++ct) {
            short8 bb = *(const short8*)(WT + (ct * 16 + m16) * 128 + k0);
            acc[0][ct] = __builtin_amdgcn_mfma_f32_16x16x32_bf16(a0, bb, acc[0][ct], 0, 0, 0);
            acc[1][ct] = __builtin_amdgcn_mfma_f32_16x16x32_bf16(a1, bb, acc[1][ct], 0, 0, 0);
        }
    }
    #pragma unroll
    for (int t2 = 0; t2 < 2; ++t2) {
        int rbase = R0 + wv * 32 + t2 * 16 + quad * 4;
        #pragma unroll
        for (int reg = 0; reg < 4; ++reg) {
            int gr = rbase + reg;
            if (gr < N_NODES) {
                #pragma unroll
                for (int ct = 0; ct < 8; ++ct)
                    C[(size_t)gr * NFEAT + ct * 16 + m16] = f2bf(acc[t2][ct][reg]);
            }
        }
    }
}

// ---------------- pass 1: self-scanning block-ranked scatter (staggered reservations) ----------------
__global__ __launch_bounds__(256) void k_p1(const int* __restrict__ src,
                                            const int* __restrict__ dst,
                                            const int* __restrict__ bcount,
                                            int* __restrict__ bstart,
                                            int* __restrict__ alloc,
                                            unsigned int* __restrict__ pairs) {
    __shared__ int hist[NCB], base[NCB], cur[NCB], bst[NCB], s[256];
    const int t = threadIdx.x;
    for (int i = t; i < NCB; i += 256) { hist[i] = 0; cur[i] = 0; }
    // local exclusive scan of bcount
    int v0 = (2 * t < NCB) ? bcount[2 * t] : 0;
    int v1 = (2 * t + 1 < NCB) ? bcount[2 * t + 1] : 0;
    int local = v0 + v1;
    s[t] = local;
    __syncthreads();
    for (int off = 1; off < 256; off <<= 1) {
        int x = (t >= off) ? s[t - off] : 0;
        __syncthreads();
        s[t] += x;
        __syncthreads();
    }
    int excl = s[t] - local;
    if (2 * t < NCB)     bst[2 * t] = excl;
    if (2 * t + 1 < NCB) bst[2 * t + 1] = excl + v0;
    if (blockIdx.x == 0) {
        if (2 * t < NCB)     bstart[2 * t] = excl;
        if (2 * t + 1 < NCB) bstart[2 * t + 1] = excl + v0;
        if (t == 255) bstart[NCB] = s[255];
    }
    __syncthreads();
    const int e0 = blockIdx.x * P1_EPB;
    const int e1 = min(e0 + P1_EPB, N_EDGES);
    for (int e = e0 + t; e < e1; e += 256)
        atomicAdd(&hist[dst[e] >> CBSHIFT], 1);
    __syncthreads();
    // staggered reservation order: spread per-bin atomic queues
    const int off0 = (blockIdx.x * 89) % NCB;
    for (int k = t; k < NCB; k += 256) {
        int i = k + off0;
        if (i >= NCB) i -= NCB;
        int c = hist[i];
        base[i] = c ? (bst[i] + atomicAdd(&alloc[i], c)) : 0;
    }
    __syncthreads();
    for (int e = e0 + t; e < e1; e += 256) {
        int d = dst[e];
        int b = d >> CBSHIFT;
        int r = atomicAdd(&cur[b], 1);
        pairs[base[b] + r] = (unsigned int)src[e] | ((unsigned int)(d & 255) << 17);
    }
}

// ---------------- pass 2: per-bucket sort -> csr_src, row_start, indeg, dinv (+sharded deg hist) ----------------
__global__ __launch_bounds__(256) void k_p2(const unsigned int* __restrict__ pairs,
                                            const int* __restrict__ bstart,
                                            int* __restrict__ csr_src,
                                            int* __restrict__ row_start,
                                            int* __restrict__ indeg,
                                            float* __restrict__ dinv,
                                            int* __restrict__ dcount) {
    __shared__ int hist[256], sst[256], cur[256], s[256], dh[64];
    const int b = blockIdx.x;
    const int t = threadIdx.x;
    const int beg = bstart[b];
    const int end = bstart[b + 1];
    hist[t] = 0; cur[t] = 0;
    if (t < 64) dh[t] = 0;
    __syncthreads();
    for (int i = beg + t; i < end; i += 256)
        atomicAdd(&hist[pairs[i] >> 17], 1);
    __syncthreads();
    int v = hist[t];
    s[t] = v;
    __syncthreads();
    for (int off = 1; off < 256; off <<= 1) {
        int x = (t >= off) ? s[t - off] : 0;
        __syncthreads();
        s[t] += x;
        __syncthreads();
    }
    sst[t] = s[t] - v;
    __syncthreads();
    {
        int node = (b << CBSHIFT) + t;
        if (node < N_NODES) {
            row_start[node] = beg + sst[t];
            indeg[node] = v;
            dinv[node] = rsqrtf((float)v + 1.0f);
            atomicAdd(&dh[63 - min(v, 63)], 1);
        }
    }
    for (int i = beg + t; i < end; i += 256) {
        unsigned int pv = pairs[i];
        int dl = pv >> 17;
        int r = atomicAdd(&cur[dl], 1);
        csr_src[beg + sst[dl] + r] = (int)(pv & 0x1FFFFu);
    }
    __syncthreads();
    if (t < 64 && dh[t]) atomicAdd(&dcount[((b & 7) << 6) + t], dh[t]);   // 8-sharded
}

// ---------------- degree permutation (descending), self-scanning over 8 shards ----------------
__global__ __launch_bounds__(256) void k_dperm(const int* __restrict__ indeg,
                                               const int* __restrict__ dcount,
                                               int* __restrict__ dalloc,
                                               int* __restrict__ perm) {
    __shared__ int h[64], base[64], cur[64], s[64];
    const int t = threadIdx.x;
    int v = 0;
    if (t < 64) {
        h[t] = 0; cur[t] = 0;
        #pragma unroll
        for (int sh = 0; sh < 8; ++sh) v += dcount[(sh << 6) + t];
        s[t] = v;
    }
    __syncthreads();
    for (int off = 1; off < 64; off <<= 1) {
        int x = (t >= off && t < 64) ? s[t - off] : 0;
        __syncthreads();
        if (t < 64) s[t] += x;
        __syncthreads();
    }
    int myst = (t < 64) ? s[t] - v : 0;
    const int i0 = blockIdx.x * DP_NPB;
    const int i1 = min(i0 + DP_NPB, N_NODES);
    for (int i = i0 + t; i < i1; i += 256)
        atomicAdd(&h[63 - min(indeg[i], 63)], 1);
    __syncthreads();
    if (t < 64) {
        int c = h[t];
        base[t] = c ? (myst + atomicAdd(&dalloc[t], c)) : 0;
    }
    __syncthreads();
    for (int i = i0 + t; i < i1; i += 256) {
        int bin = 63 - min(indeg[i], 63);
        int r = atomicAdd(&cur[bin], 1);
        perm[base[bin] + r] = i;
    }
}

// ---------------- gather layer 1 (per-edge dinv) + fused z projection; persistent ----------------
__global__ __launch_bounds__(256) void k_gather1(const unsigned short* __restrict__ xwb,
                                                 const int* __restrict__ csr_src,
                                                 const int* __restrict__ row_start,
                                                 const int* __restrict__ indeg,
                                                 const float* __restrict__ dinv,
                                                 const float* __restrict__ b,
                                                 const float* __restrict__ w2l,
                                                 const int* __restrict__ perm,
                                                 float* __restrict__ z) {
    const int lane  = threadIdx.x & 63;
    const int p     = lane & 15;
    const int gbase = lane & 48;
    const int ngroups = G1_BLOCKS * 16;
    int gid = blockIdx.x * 16 + (threadIdx.x >> 4);
    const uint4* tab = (const uint4*)xwb;
    float4 b0 = *(const float4*)(b + p * 8);
    float4 b1 = *(const float4*)(b + p * 8 + 4);
    float4 w0 = *(const float4*)(w2l + p * 8);
    float4 w1 = *(const float4*)(w2l + p * 8 + 4);

    for (int nidx = gid; nidx < N_NODES; nidx += ngroups) {
        int node = perm[nidx];
        const int beg = row_start[node];
        const int cnt = indeg[node];
        float dvn = dinv[node];
        float acc[8] = {};
        acc8s(acc, tab[(size_t)node * 16 + p], dvn);     // self loop
        int j = 0;
        #pragma unroll 1
        for (; j + 8 <= cnt; j += 8) {
            int   my   = csr_src[beg + j + (p & 7)];
            float mydv = dinv[my];
            uint4 v[8];
            #pragma unroll
            for (int q = 0; q < 8; ++q) {
                int idx = __shfl(my, gbase + q);
                v[q] = tab[(size_t)idx * 16 + p];
            }
            #pragma unroll
            for (int q = 0; q < 8; ++q) {
                float sv = __shfl(mydv, gbase + q);
                acc8s(acc, v[q], sv);
            }
        }
        #pragma unroll 1
        for (; j < cnt; ++j) {
            int idx = csr_src[beg + j];
            float sv = dinv[idx];
            acc8s(acc, tab[(size_t)idx * 16 + p], sv);
        }
        float s = fmaxf(acc[0] * dvn + b0.x, 0.f) * w0.x
                + fmaxf(acc[1] * dvn + b0.y, 0.f) * w0.y
                + fmaxf(acc[2] * dvn + b0.z, 0.f) * w0.z
                + fmaxf(acc[3] * dvn + b0.w, 0.f) * w0.w
                + fmaxf(acc[4] * dvn + b1.x, 0.f) * w1.x
                + fmaxf(acc[5] * dvn + b1.y, 0.f) * w1.y
                + fmaxf(acc[6] * dvn + b1.z, 0.f) * w1.z
                + fmaxf(acc[7] * dvn + b1.w, 0.f) * w1.w;
        s += __shfl_xor(s, 1);
        s += __shfl_xor(s, 2);
        s += __shfl_xor(s, 4);
        s += __shfl_xor(s, 8);
        if (p == 0) z[node] = s * dvn;
    }
}

// ---------------- layer 2 + pool over scalars ----------------
__global__ __launch_bounds__(256) void k_gather2s(const float* __restrict__ z,
                                                  const int* __restrict__ csr_src,
                                                  const int* __restrict__ row_start,
                                                  const int* __restrict__ indeg,
                                                  const float* __restrict__ dinv,
                                                  const int* __restrict__ perm,
                                                  const int* __restrict__ batch,
                                                  float* __restrict__ gsum) {
    int nidx = blockIdx.x * blockDim.x + threadIdx.x;
    if (nidx >= N_NODES) return;
    int node = perm[nidx];
    const int beg = row_start[node];
    const int cnt = indeg[node];
    float a = z[node];
    int j = 0;
    #pragma unroll 1
    for (; j + 4 <= cnt; j += 4) {
        int i0 = csr_src[beg + j + 0];
        int i1 = csr_src[beg + j + 1];
        int i2 = csr_src[beg + j + 2];
        int i3 = csr_src[beg + j + 3];
        a += z[i0] + z[i1] + z[i2] + z[i3];
    }
    #pragma unroll 1
    for (; j < cnt; ++j)
        a += z[csr_src[beg + j]];
    atomicAdd(&gsum[batch[node]], a * dinv[node]);
}

// ---------------- final: counts via binary search on sorted batch; +c2 ----------------
__global__ void k_final(const float* __restrict__ gsum, const int* __restrict__ batch,
                        const float* __restrict__ c2, float* __restrict__ out) {
    int g = blockIdx.x * blockDim.x + threadIdx.x;
    if (g >= NGRAPHS) return;
    int lo = 0, hi = N_NODES;
    while (lo < hi) { int m = (lo + hi) >> 1; if (batch[m] < g) lo = m + 1; else hi = m; }
    int lb = lo;
    lo = 0; hi = N_NODES;
    int g1 = g + 1;
    while (lo < hi) { int m = (lo + hi) >> 1; if (batch[m] < g1) lo = m + 1; else hi = m; }
    float cnt = (float)(lo - lb);
    out[g] = gsum[g] / fmaxf(cnt, 1.0f) + c2[0];
}

extern "C" void kernel_launch(void* const* d_in, const int* in_sizes, int n_in,
                              void* d_out, int out_size, void* d_ws, size_t ws_size,
                              hipStream_t stream) {
    const float* x    = (const float*)d_in[0];
    const int*   ei   = (const int*)d_in[1];
    const int*   bat  = (const int*)d_in[2];
    const float* W1   = (const float*)d_in[3];
    const float* b1   = (const float*)d_in[4];
    const float* W2   = (const float*)d_in[5];
    const float* b2   = (const float*)d_in[6];
    const float* Wlin = (const float*)d_in[7];
    const float* blin = (const float*)d_in[8];
    float* out = (float*)d_out;

    const int* src = ei;
    const int* dst = ei + N_EDGES;

    // ---- workspace layout ----
    const size_t NF = (size_t)N_NODES * NFEAT;
    unsigned short* bufA = (unsigned short*)d_ws;          // bf16 xw1 table (unscaled)
    float* z       = (float*)(bufA + NF);                  // [N]
    float* dinv    = z + N_NODES;                          // [N]
    int* row_start = (int*)(dinv + N_NODES);               // [N]
    int* indeg     = row_start + N_NODES;                  // [N]
    int* perm      = indeg + N_NODES;                      // [N]
    int* bstart    = perm + N_NODES;                       // [NCB+1]
    // zeroed-by-misc region (contiguous): gsum | alloc | dalloc | dcount(8x64) | bcount
    float* gsum    = (float*)(bstart + NCB + 1);           // [G]
    int* alloc     = (int*)(gsum + NGRAPHS);               // [NCB]
    int* dalloc    = alloc + NCB;                          // [64]
    int* dcount    = dalloc + 64;                          // [512]
    int* bcount    = dcount + 512;                         // [NCB]
    unsigned short* WT1 = (unsigned short*)(bcount + NCB); // [16384]
    float* w2l     = (float*)(WT1 + 128 * 128);            // [132] (c2 at [128])
    unsigned int* pairs = (unsigned int*)(w2l + 132);      // [E]
    int* csr_src   = (int*)(pairs + N_EDGES);              // [E]

    const int BS = 256;
    int p1_blocks   = (N_EDGES + P1_EPB - 1) / P1_EPB;     // 196
    int node_blocks = (N_NODES + BS - 1) / BS;
    int misc_blocks = 17 + (ZCNT + BS - 1) / BS;           // 17 + 14 = 31

    // ---- setup (weights + zeroing), then fused GEMM || bucket histogram ----
    k_misc<<<misc_blocks, BS, 0, stream>>>(W1, WT1, W2, Wlin, b2, blin, w2l, (int*)gsum);
    k_gemm_bhist<<<GEMM_BLOCKS + BH_BLOCKS, BS, 0, stream>>>(x, WT1, bufA, dst, bcount);

    // ---- CSR build ----
    k_p1<<<p1_blocks, BS, 0, stream>>>(src, dst, bcount, bstart, alloc, pairs);
    k_p2<<<NCB, BS, 0, stream>>>(pairs, bstart, csr_src, row_start, indeg, dinv, dcount);
    k_dperm<<<DP_BLOCKS, BS, 0, stream>>>(indeg, dcount, dalloc, perm);

    // ---- layer 1 gather (+ fused layer-2 projection to scalar z) ----
    k_gather1<<<G1_BLOCKS, BS, 0, stream>>>(bufA, csr_src, row_start, indeg, dinv, b1, w2l,
                                            perm, z);

    // ---- layer 2 + pool over scalar z ----
    k_gather2s<<<node_blocks, BS, 0, stream>>>(z, csr_src, row_start, indeg, dinv, perm,
                                               bat, gsum);

    // ---- final ----
    k_final<<<(NGRAPHS + BS - 1) / BS, BS, 0, stream>>>(gsum, bat, w2l + 128, out);
}